// Round 7
// baseline (739.778 us; speedup 1.0000x reference)
//
#include <hip/hip_runtime.h>
#include <hip/hip_bf16.h>

// ---------------------------------------------------------------------------
// GIN forward (all I/O fp32):
//   2x GINConv(128->128->128, eps=0) + ReLU, L2 row-normalize,
//   per-node MLP 128->32->32->32, per-graph Gram (32x32 -> 1024),
//   per-graph MLP 1024->32->32->2.
// Internals: node features bf16, fp32 accumulate.
// Aggregation: bucket-binned edges -> per-bucket LDS counting sort ->
// full-wave gather, 8 loads in flight.
// GINConv: both GEMMs fused in one kernel (h1 stays in LDS).
// Tail: separate norm_mlp / gram / graph_mlp (r4-proven; fused tail was a
// 168us barrier-serialization regression at 2 blocks/CU -- reverted).
// ---------------------------------------------------------------------------

#define NN 131072      // nodes
#define NE 2097152     // edges
#define NG 512         // graphs
#define NB 1024        // buckets (128 nodes each)
#define BCH 16384      // edges per binning block (NE/128)
#define CAP 3072       // edge-sort chunk capacity (bucket avg 2048, sigma ~45)

typedef unsigned short u16;
typedef unsigned int u32;
typedef __attribute__((ext_vector_type(8))) short short8;   // 8 x bf16
typedef __attribute__((ext_vector_type(4))) float f32x4;

__device__ __forceinline__ float bf2f(u16 u) {
    union { u32 i; float f; } x; x.i = ((u32)u) << 16; return x.f;
}
__device__ __forceinline__ u16 f2bf(float f) {
    union { u32 i; float f; } x; x.f = f;
    u32 r = x.i + 0x7fffu + ((x.i >> 16) & 1u);   // RNE
    return (u16)(r >> 16);
}

// ---------------- cast x: fp32 -> bf16 ----------------
__global__ __launch_bounds__(256) void cast_x(const float* __restrict__ xf,
                                              u16* __restrict__ xb) {
    int i = blockIdx.x * 256 + threadIdx.x;       // 8 floats per thread
    const float4* src = (const float4*)xf;
    float4 a = src[2 * i], b = src[2 * i + 1];
    uint4 o;
    o.x = (u32)f2bf(a.x) | ((u32)f2bf(a.y) << 16);
    o.y = (u32)f2bf(a.z) | ((u32)f2bf(a.w) << 16);
    o.z = (u32)f2bf(b.x) | ((u32)f2bf(b.y) << 16);
    o.w = (u32)f2bf(b.z) | ((u32)f2bf(b.w) << 16);
    ((uint4*)xb)[i] = o;
}

// ---------------- edge binning: count per bucket ----------------
__global__ __launch_bounds__(256) void bin_count(const int* __restrict__ gdst,
                                                 int* __restrict__ bcnt) {
    __shared__ int bc[NB];
    int t = threadIdx.x;
    for (int i = 0; i < 4; ++i) bc[t + i * 256] = 0;
    __syncthreads();
    int base = blockIdx.x * BCH;
    for (int i = 0; i < BCH / 256; ++i) {
        int d = gdst[base + i * 256 + t];
        atomicAdd(&bc[d >> 7], 1);
    }
    __syncthreads();
    for (int i = 0; i < 4; ++i) {
        int b = t + i * 256;
        if (bc[b]) atomicAdd(&bcnt[b], bc[b]);
    }
}

// ---------------- scan over 1024 buckets ----------------
__global__ __launch_bounds__(1024) void scan_buckets(const int* __restrict__ bcnt,
                                                     int* __restrict__ bbase,
                                                     int* __restrict__ cursor) {
    __shared__ int tmp[NB];
    int t = threadIdx.x;
    tmp[t] = bcnt[t];
    __syncthreads();
    for (int o = 1; o < NB; o <<= 1) {
        int u = (t >= o) ? tmp[t - o] : 0;
        __syncthreads();
        tmp[t] += u;
        __syncthreads();
    }
    int ex = tmp[t] - bcnt[t];
    bbase[t] = ex;
    cursor[t] = ex;
    if (t == NB - 1) bbase[NB] = tmp[t];
}

// ---------------- scatter edges into bucket-grouped array ----------------
// ebuf[e] = (src << 7) | (dst & 127), grouped by bucket = dst >> 7
__global__ __launch_bounds__(256) void bin_scatter(const int* __restrict__ gsrc,
                                                   const int* __restrict__ gdst,
                                                   int* __restrict__ cursor,
                                                   u32* __restrict__ ebuf) {
    __shared__ int lc[NB];   // local counts
    __shared__ int rb[NB];   // reserved run base (global)
    __shared__ int lb[NB];   // local bump
    int t = threadIdx.x;
    for (int i = 0; i < 4; ++i) lc[t + i * 256] = 0;
    __syncthreads();
    int base = blockIdx.x * BCH;
    for (int i = 0; i < BCH / 256; ++i) {
        int d = gdst[base + i * 256 + t];
        atomicAdd(&lc[d >> 7], 1);
    }
    __syncthreads();
    for (int i = 0; i < 4; ++i) {
        int b = t + i * 256;
        int c = lc[b];
        rb[b] = c ? atomicAdd(&cursor[b], c) : 0;
        lb[b] = 0;
    }
    __syncthreads();
    for (int i = 0; i < BCH / 256; ++i) {
        int idx = base + i * 256 + t;
        int d = gdst[idx];
        int s = gsrc[idx];
        int b = d >> 7;
        int o = atomicAdd(&lb[b], 1);
        ebuf[rb[b] + o] = ((u32)s << 7) | (u32)(d & 127);
    }
}

// ---------------- aggregation: T[i] = X[i] + sum_{j->i} X[j] ----------------
// Block = one bucket (128 nodes), 8 waves, 16 nodes/wave.
// Full-wave gather, 8 independent loads in flight.
__global__ __launch_bounds__(512) void aggregate_bucket(const u16* __restrict__ X,
                                                        const u32* __restrict__ ebuf,
                                                        const int* __restrict__ bbase,
                                                        u16* __restrict__ T) {
    __shared__ int lcnt[128];
    __shared__ int lstart[128];
    __shared__ int lofs[128];
    __shared__ int sorted[CAP];
    int t = threadIdx.x, lane = t & 63, wave = t >> 6;   // 8 waves
    int bkt = blockIdx.x;
    const u32* Xu = (const u32*)X;

    // init register accumulators with own row (eps=0 self term)
    float a0[16], a1[16];
#pragma unroll
    for (int i = 0; i < 16; ++i) {
        int row = bkt * 128 + wave * 16 + i;
        u32 v = Xu[(size_t)row * 64 + lane];
        a0[i] = bf2f((u16)v);
        a1[i] = bf2f((u16)(v >> 16));
    }

    int e0 = bbase[bkt], e1 = bbase[bkt + 1];
    for (int cs = e0; cs < e1; cs += CAP) {
        int n = min(CAP, e1 - cs);
        if (t < 128) lcnt[t] = 0;
        __syncthreads();
        for (int j = t; j < n; j += 512)
            atomicAdd(&lcnt[ebuf[cs + j] & 127], 1);
        __syncthreads();
        if (wave == 0) {                         // exclusive scan of 128 counts
            int c0 = lcnt[2 * lane], c1 = lcnt[2 * lane + 1];
            int s = c0 + c1, e = s;
            for (int o = 1; o < 64; o <<= 1) {
                int u = __shfl_up(e, o, 64);
                if (lane >= o) e += u;
            }
            int excl = e - s;
            lstart[2 * lane] = excl;          lofs[2 * lane] = excl;
            lstart[2 * lane + 1] = excl + c0; lofs[2 * lane + 1] = excl + c0;
        }
        __syncthreads();
        for (int j = t; j < n; j += 512) {       // place: node-sorted src list
            u32 e = ebuf[cs + j];
            int pos = atomicAdd(&lofs[e & 127], 1);
            sorted[pos] = (int)(e >> 7);
        }
        __syncthreads();
        // gather + accumulate (no atomics; sorted[] reads are wave-broadcast)
#pragma unroll
        for (int i = 0; i < 16; ++i) {
            int node = wave * 16 + i;
            int p = lstart[node], pe = p + lcnt[node];
            for (; p + 8 <= pe; p += 8) {        // 8 loads in flight
                int s[8];
#pragma unroll
                for (int k = 0; k < 8; ++k) s[k] = sorted[p + k];
                u32 w[8];
#pragma unroll
                for (int k = 0; k < 8; ++k) w[k] = Xu[(size_t)s[k] * 64 + lane];
#pragma unroll
                for (int k = 0; k < 8; ++k) {
                    a0[i] += bf2f((u16)w[k]);
                    a1[i] += bf2f((u16)(w[k] >> 16));
                }
            }
            for (; p < pe; ++p) {
                u32 w = Xu[(size_t)sorted[p] * 64 + lane];
                a0[i] += bf2f((u16)w);
                a1[i] += bf2f((u16)(w >> 16));
            }
        }
        __syncthreads();                         // protect lcnt/sorted for next chunk
    }

    u32* Tu = (u32*)T;
#pragma unroll
    for (int i = 0; i < 16; ++i) {
        int row = bkt * 128 + wave * 16 + i;
        Tu[(size_t)row * 64 + lane] = (u32)f2bf(a0[i]) | ((u32)f2bf(a1[i]) << 16);
    }
}

// ---------------- weight transpose + cast: Wt[n][k] = (bf16)W[k][n] ----------------
__global__ __launch_bounds__(256) void transpose_w(const float* a, const float* b,
                                                   const float* c, const float* d, u16* Wt) {
    const float* w = (blockIdx.x == 0) ? a : (blockIdx.x == 1) ? b : (blockIdx.x == 2) ? c : d;
    u16* o = Wt + blockIdx.x * 16384;
    for (int i = 0; i < 64; ++i) {
        int idx = threadIdx.x + i * 256;
        o[(idx & 127) * 128 + (idx >> 7)] = f2bf(w[idx]);
    }
}

// ---------------- fused GINConv MLP: C = relu(relu(A@W1+b1)@W2+b2) ----------------
__global__ __launch_bounds__(256) void gemm2_relu(const u16* __restrict__ A,
                                                  const u16* __restrict__ Wt1,
                                                  const u16* __restrict__ Wt2,
                                                  const float* __restrict__ b1,
                                                  const float* __restrict__ b2,
                                                  u16* __restrict__ C) {
    __shared__ u16 As[64][136];     // A tile, then h1 (overwritten in place)
    __shared__ u16 W1s[128][136];
    __shared__ u16 W2s[128][136];
    int tid = threadIdx.x;
    size_t rowBase = (size_t)blockIdx.x * 64;

    // issue W2 global loads early; ds_write after gemm1 (overlap)
    uint4 w2r[8];
#pragma unroll
    for (int i = 0; i < 8; ++i) {
        int c = tid + i * 256;
        w2r[i] = *(const uint4*)(Wt2 + (c >> 4) * 128 + ((c & 15) << 3));
    }
    for (int i = 0; i < 4; ++i) {
        int c = tid + i * 256;
        int r = c >> 4, co = (c & 15) << 3;
        *(uint4*)&As[r][co] = *(const uint4*)(A + (rowBase + r) * 128 + co);
    }
    for (int i = 0; i < 8; ++i) {
        int c = tid + i * 256;
        int r = c >> 4, co = (c & 15) << 3;
        *(uint4*)&W1s[r][co] = *(const uint4*)(Wt1 + r * 128 + co);
    }
    __syncthreads();

    int lane = tid & 63, wave = tid >> 6;
    int quad = lane >> 4, l16 = lane & 15;

    f32x4 acc[8];
#pragma unroll
    for (int t = 0; t < 8; ++t) acc[t] = (f32x4){0.f, 0.f, 0.f, 0.f};
#pragma unroll
    for (int c = 0; c < 4; ++c) {
        short8 a = *(const short8*)&As[wave * 16 + l16][c * 32 + quad * 8];
#pragma unroll
        for (int t = 0; t < 8; ++t) {
            short8 b = *(const short8*)&W1s[t * 16 + l16][c * 32 + quad * 8];
            acc[t] = __builtin_amdgcn_mfma_f32_16x16x32_bf16(a, b, acc[t], 0, 0, 0);
        }
    }

    // stage W2 into LDS (loads already in flight)
#pragma unroll
    for (int i = 0; i < 8; ++i) {
        int c = tid + i * 256;
        *(uint4*)&W2s[c >> 4][(c & 15) << 3] = w2r[i];
    }
    // h1 = relu(acc + b1) -> back into As (each wave writes only its 16 rows)
#pragma unroll
    for (int t = 0; t < 8; ++t) {
        int col = t * 16 + l16;
        float bv = b1[col];
#pragma unroll
        for (int r = 0; r < 4; ++r)
            As[wave * 16 + quad * 4 + r][col] = f2bf(fmaxf(acc[t][r] + bv, 0.f));
    }
    __syncthreads();

    f32x4 acc2[8];
#pragma unroll
    for (int t = 0; t < 8; ++t) acc2[t] = (f32x4){0.f, 0.f, 0.f, 0.f};
#pragma unroll
    for (int c = 0; c < 4; ++c) {
        short8 a = *(const short8*)&As[wave * 16 + l16][c * 32 + quad * 8];
#pragma unroll
        for (int t = 0; t < 8; ++t) {
            short8 b = *(const short8*)&W2s[t * 16 + l16][c * 32 + quad * 8];
            acc2[t] = __builtin_amdgcn_mfma_f32_16x16x32_bf16(a, b, acc2[t], 0, 0, 0);
        }
    }
#pragma unroll
    for (int t = 0; t < 8; ++t) {
        int col = t * 16 + l16;
        float bv = b2[col];
#pragma unroll
        for (int r = 0; r < 4; ++r) {
            int row = wave * 16 + quad * 4 + r;
            C[(rowBase + row) * 128 + col] = f2bf(fmaxf(acc2[t][r] + bv, 0.f));
        }
    }
}

// ---------------- normalize + per-node MLP (128->32->32->32), fp32 weights ----------------
__global__ __launch_bounds__(256) void norm_mlp(const u16* __restrict__ X,
                                                const float* Ws1, const float* bs1,
                                                const float* Ws2, const float* bs2,
                                                const float* Ws3, const float* bs3,
                                                float* __restrict__ S) {
    __shared__ float W1s[128 * 32];
    __shared__ float W2s[32 * 32];
    __shared__ float W3s[32 * 32];
    __shared__ float b1s[32], b2s[32], b3s[32];
    __shared__ float hbuf[4][128];
    __shared__ float sbuf[4][32];
    int t = threadIdx.x;
    for (int i = 0; i < 16; ++i) W1s[t + i * 256] = Ws1[t + i * 256];
    for (int i = 0; i < 4; ++i) { W2s[t + i * 256] = Ws2[t + i * 256]; W3s[t + i * 256] = Ws3[t + i * 256]; }
    if (t < 32) { b1s[t] = bs1[t]; b2s[t] = bs2[t]; b3s[t] = bs3[t]; }
    __syncthreads();

    int wave = t >> 6, lane = t & 63;
    int node = blockIdx.x * 4 + wave;
    u32 v = ((const u32*)X)[(size_t)node * 64 + lane];
    float f0 = bf2f((u16)v), f1 = bf2f((u16)(v >> 16));
    float ss = f0 * f0 + f1 * f1;
    for (int o = 1; o < 64; o <<= 1) ss += __shfl_xor(ss, o, 64);
    float inv = 1.0f / fmaxf(sqrtf(ss), 1e-12f);
    hbuf[wave][2 * lane] = f0 * inv;
    hbuf[wave][2 * lane + 1] = f1 * inv;
    __syncthreads();

    int j = lane & 31, half = lane >> 5;
    float p = 0.f;
    for (int i = 0; i < 64; ++i) { int k = half * 64 + i; p += hbuf[wave][k] * W1s[k * 32 + j]; }
    p += __shfl_xor(p, 32, 64);
    float s1 = fmaxf(p + b1s[j], 0.f);
    if (!half) sbuf[wave][j] = s1;
    __syncthreads();

    p = 0.f;
    for (int i = 0; i < 16; ++i) { int k = half * 16 + i; p += sbuf[wave][k] * W2s[k * 32 + j]; }
    p += __shfl_xor(p, 32, 64);
    float s2 = fmaxf(p + b2s[j], 0.f);
    __syncthreads();
    if (!half) sbuf[wave][j] = s2;
    __syncthreads();

    p = 0.f;
    for (int i = 0; i < 16; ++i) { int k = half * 16 + i; p += sbuf[wave][k] * W3s[k * 32 + j]; }
    p += __shfl_xor(p, 32, 64);
    float s3 = fmaxf(p + b3s[j], 0.f);
    if (!half) S[(size_t)node * 32 + j] = s3;
}

// ---------------- per-graph Gram: out[g][f][e] = sum_n S[g,n,f]*S[g,n,e] ----------------
__global__ __launch_bounds__(256) void gram(const float* __restrict__ S,
                                            float* __restrict__ out) {
    __shared__ float Sg[256 * 32];
    int t = threadIdx.x, g = blockIdx.x;
    const float4* src = (const float4*)(S + (size_t)g * 8192);
    float4* dst = (float4*)Sg;
    for (int i = 0; i < 8; ++i) dst[t + i * 256] = src[t + i * 256];
    __syncthreads();

    int f = t >> 3, e0 = (t & 7) << 2;
    float4 a = {0.f, 0.f, 0.f, 0.f};
    for (int n = 0; n < 256; ++n) {
        float sf = Sg[n * 32 + f];
        float4 se = *(const float4*)&Sg[n * 32 + e0];
        a.x += sf * se.x; a.y += sf * se.y; a.z += sf * se.z; a.w += sf * se.w;
    }
    *(float4*)(out + (size_t)g * 1024 + f * 32 + e0) = a;
}

// ---------------- per-graph MLP: 1024->32->32->2 (fp32) ----------------
__global__ __launch_bounds__(256) void graph_mlp(const float* __restrict__ HH,
                                                 const float* Wm1, const float* bm1,
                                                 const float* Wm2, const float* bm2,
                                                 const float* Wm3, const float* bm3,
                                                 float* __restrict__ out) {
    __shared__ float hh[1024];
    __shared__ float red[256];
    __shared__ float o1[32];
    __shared__ float o2[32];
    int t = threadIdx.x, g = blockIdx.x;
    ((float4*)hh)[t] = ((const float4*)(HH + (size_t)g * 1024))[t];
    __syncthreads();

    int j = t & 31, part = t >> 5;
    float p = 0.f;
    for (int i = 0; i < 128; ++i) { int k = part * 128 + i; p += hh[k] * Wm1[k * 32 + j]; }
    red[t] = p;
    __syncthreads();
    if (t < 32) {
        float s = 0.f;
        for (int q = 0; q < 8; ++q) s += red[q * 32 + t];
        o1[t] = fmaxf(s + bm1[t], 0.f);
    }
    __syncthreads();
    if (t < 32) {
        float s = 0.f;
        for (int k = 0; k < 32; ++k) s += o1[k] * Wm2[k * 32 + t];
        o2[t] = fmaxf(s + bm2[t], 0.f);
    }
    __syncthreads();
    if (t < 2) {
        float s = 0.f;
        for (int k = 0; k < 32; ++k) s += o2[k] * Wm3[k * 2 + t];
        out[524288 + g * 2 + t] = fmaxf(s + bm3[t], 0.f);
    }
}

// ---------------------------------------------------------------------------
extern "C" void kernel_launch(void* const* d_in, const int* in_sizes, int n_in,
                              void* d_out, int out_size, void* d_ws, size_t ws_size,
                              hipStream_t stream) {
    const float* x   = (const float*)d_in[0];
    const int*   ei  = (const int*)d_in[1];
    const float* W1a = (const float*)d_in[2];  const float* b1a = (const float*)d_in[3];
    const float* W2a = (const float*)d_in[4];  const float* b2a = (const float*)d_in[5];
    const float* W1b = (const float*)d_in[6];  const float* b1b = (const float*)d_in[7];
    const float* W2b = (const float*)d_in[8];  const float* b2b = (const float*)d_in[9];
    const float* Ws1 = (const float*)d_in[10]; const float* bs1 = (const float*)d_in[11];
    const float* Ws2 = (const float*)d_in[12]; const float* bs2 = (const float*)d_in[13];
    const float* Ws3 = (const float*)d_in[14]; const float* bs3 = (const float*)d_in[15];
    const float* Wm1 = (const float*)d_in[16]; const float* bm1 = (const float*)d_in[17];
    const float* Wm2 = (const float*)d_in[18]; const float* bm2 = (const float*)d_in[19];
    const float* Wm3 = (const float*)d_in[20]; const float* bm3 = (const float*)d_in[21];
    float* out = (float*)d_out;

    const int* gsrc = ei;
    const int* gdst = ei + NE;

    char* ws = (char*)d_ws;
    size_t off = 0;
    auto alloc = [&](size_t bytes) { size_t r = off; off = (off + bytes + 255) & ~(size_t)255; return r; };
    int*  bcnt   = (int*)(ws + alloc((size_t)NB * 4));
    int*  bbase  = (int*)(ws + alloc((size_t)(NB + 1) * 4));
    int*  cursor = (int*)(ws + alloc((size_t)NB * 4));
    u32*  ebuf   = (u32*)(ws + alloc((size_t)NE * 4));
    u16*  Wt     = (u16*)(ws + alloc(4 * 16384 * 2));
    u16*  X0     = (u16*)(ws + alloc((size_t)NN * 128 * 2));   // xb / hA / hB
    u16*  B1     = (u16*)(ws + alloc((size_t)NN * 128 * 2));   // aggregated T
    float* S     = (float*)B1;                                  // alias: B1 dead after last gemm2
    (void)ws_size; (void)n_in; (void)in_sizes; (void)out_size;

    // ---- edge binning ----
    hipMemsetAsync(bcnt, 0, (size_t)NB * 4, stream);
    bin_count<<<NE / BCH, 256, 0, stream>>>(gdst, bcnt);
    scan_buckets<<<1, 1024, 0, stream>>>(bcnt, bbase, cursor);
    bin_scatter<<<NE / BCH, 256, 0, stream>>>(gsrc, gdst, cursor, ebuf);

    // ---- casts ----
    cast_x<<<NN * 128 / (256 * 8), 256, 0, stream>>>(x, X0);
    transpose_w<<<4, 256, 0, stream>>>(W1a, W2a, W1b, W2b, Wt);

    // ---- layer A ----
    aggregate_bucket<<<NB, 512, 0, stream>>>(X0, ebuf, bbase, B1);
    gemm2_relu<<<NN / 64, 256, 0, stream>>>(B1, Wt + 0 * 16384, Wt + 1 * 16384, b1a, b2a, X0);
    // ---- layer B ----
    aggregate_bucket<<<NB, 512, 0, stream>>>(X0, ebuf, bbase, B1);
    gemm2_relu<<<NN / 64, 256, 0, stream>>>(B1, Wt + 2 * 16384, Wt + 3 * 16384, b1b, b2b, X0);

    // ---- tail: normalize + node MLP (S aliases B1), Gram -> out, graph MLP ----
    norm_mlp<<<NN / 4, 256, 0, stream>>>(X0, Ws1, bs1, Ws2, bs2, Ws3, bs3, S);
    gram<<<NG, 256, 0, stream>>>(S, out);
    graph_mlp<<<NG, 256, 0, stream>>>(out, Wm1, bm1, Wm2, bm2, Wm3, bm3, out);
}

// Round 8
// 658.041 us; speedup vs baseline: 1.1242x; 1.1242x over previous
//
#include <hip/hip_runtime.h>
#include <hip/hip_bf16.h>

// ---------------------------------------------------------------------------
// GIN forward (all I/O fp32):
//   2x GINConv(128->128->128, eps=0) + ReLU, L2 row-normalize,
//   per-node MLP 128->32->32->32, per-graph Gram (32x32 -> 1024),
//   per-graph MLP 1024->32->32->2.
// Internals: node features bf16, fp32 accumulate.
// Binning: direct scatter into fixed 4096-capacity bucket regions (no count
// pass, no scan; counts ~2048+-45 so 4096 cap is unreachable).
// Aggregation: per-bucket LDS counting sort -> full-wave register gather.
// GINConv: fused 2-GEMM kernel; W2 reuses W1's LDS (52KB -> 3 blocks/CU).
// ---------------------------------------------------------------------------

#define NN 131072      // nodes
#define NE 2097152     // edges
#define NG 512         // graphs
#define NB 1024        // buckets (128 nodes each)
#define BCAP 4096      // fixed ebuf capacity per bucket
#define ECH 8192       // edges per scatter block (NE/256)
#define CAP 3072       // edge-sort chunk capacity (bucket avg 2048, sigma ~45)

typedef unsigned short u16;
typedef unsigned int u32;
typedef __attribute__((ext_vector_type(8))) short short8;   // 8 x bf16
typedef __attribute__((ext_vector_type(4))) float f32x4;

__device__ __forceinline__ float bf2f(u16 u) {
    union { u32 i; float f; } x; x.i = ((u32)u) << 16; return x.f;
}
__device__ __forceinline__ u16 f2bf(float f) {
    union { u32 i; float f; } x; x.f = f;
    u32 r = x.i + 0x7fffu + ((x.i >> 16) & 1u);   // RNE
    return (u16)(r >> 16);
}

// ---------------- cast x: fp32 -> bf16 ----------------
__global__ __launch_bounds__(256) void cast_x(const float* __restrict__ xf,
                                              u16* __restrict__ xb) {
    int i = blockIdx.x * 256 + threadIdx.x;       // 8 floats per thread
    const float4* src = (const float4*)xf;
    float4 a = src[2 * i], b = src[2 * i + 1];
    uint4 o;
    o.x = (u32)f2bf(a.x) | ((u32)f2bf(a.y) << 16);
    o.y = (u32)f2bf(a.z) | ((u32)f2bf(a.w) << 16);
    o.z = (u32)f2bf(b.x) | ((u32)f2bf(b.y) << 16);
    o.w = (u32)f2bf(b.z) | ((u32)f2bf(b.w) << 16);
    ((uint4*)xb)[i] = o;
}

// ---------------- cursor init: cursor[b] = b * BCAP ----------------
__global__ __launch_bounds__(256) void init_cursor(int* __restrict__ cursor) {
    int b = blockIdx.x * 256 + threadIdx.x;
    cursor[b] = b * BCAP;
}

// ---------------- direct scatter into bucket regions ----------------
// ebuf[bucket region b*BCAP ...] = (src << 7) | (dst & 127)
__global__ __launch_bounds__(256) void bin_scatter(const int* __restrict__ gsrc,
                                                   const int* __restrict__ gdst,
                                                   int* __restrict__ cursor,
                                                   u32* __restrict__ ebuf) {
    __shared__ int lc[NB];   // local counts
    __shared__ int rb[NB];   // reserved run base (global)
    __shared__ int lb[NB];   // local bump
    int t = threadIdx.x;
    for (int i = 0; i < 4; ++i) lc[t + i * 256] = 0;
    __syncthreads();
    int base = blockIdx.x * ECH;
    for (int i = 0; i < ECH / 256; ++i) {
        int d = gdst[base + i * 256 + t];
        atomicAdd(&lc[d >> 7], 1);
    }
    __syncthreads();
    for (int i = 0; i < 4; ++i) {
        int b = t + i * 256;
        int c = lc[b];
        rb[b] = c ? atomicAdd(&cursor[b], c) : 0;
        lb[b] = 0;
    }
    __syncthreads();
    for (int i = 0; i < ECH / 256; ++i) {
        int idx = base + i * 256 + t;
        int d = gdst[idx];
        int s = gsrc[idx];
        int b = d >> 7;
        int o = atomicAdd(&lb[b], 1);
        ebuf[rb[b] + o] = ((u32)s << 7) | (u32)(d & 127);
    }
}

// ---------------- aggregation: T[i] = X[i] + sum_{j->i} X[j] ----------------
// Block = one bucket (128 nodes), 8 waves, 16 nodes/wave.
// Full-wave gather, 8 independent loads in flight.
__global__ __launch_bounds__(512) void aggregate_bucket(const u16* __restrict__ X,
                                                        const u32* __restrict__ ebuf,
                                                        const int* __restrict__ bcur,
                                                        u16* __restrict__ T) {
    __shared__ int lcnt[128];
    __shared__ int lstart[128];
    __shared__ int lofs[128];
    __shared__ int sorted[CAP];
    int t = threadIdx.x, lane = t & 63, wave = t >> 6;   // 8 waves
    int bkt = blockIdx.x;
    const u32* Xu = (const u32*)X;

    // init register accumulators with own row (eps=0 self term)
    float a0[16], a1[16];
#pragma unroll
    for (int i = 0; i < 16; ++i) {
        int row = bkt * 128 + wave * 16 + i;
        u32 v = Xu[(size_t)row * 64 + lane];
        a0[i] = bf2f((u16)v);
        a1[i] = bf2f((u16)(v >> 16));
    }

    int e0 = bkt * BCAP, e1 = bcur[bkt];       // cursor holds base+count after scatter
    for (int cs = e0; cs < e1; cs += CAP) {
        int n = min(CAP, e1 - cs);
        if (t < 128) lcnt[t] = 0;
        __syncthreads();
        for (int j = t; j < n; j += 512)
            atomicAdd(&lcnt[ebuf[cs + j] & 127], 1);
        __syncthreads();
        if (wave == 0) {                         // exclusive scan of 128 counts
            int c0 = lcnt[2 * lane], c1 = lcnt[2 * lane + 1];
            int s = c0 + c1, e = s;
            for (int o = 1; o < 64; o <<= 1) {
                int u = __shfl_up(e, o, 64);
                if (lane >= o) e += u;
            }
            int excl = e - s;
            lstart[2 * lane] = excl;          lofs[2 * lane] = excl;
            lstart[2 * lane + 1] = excl + c0; lofs[2 * lane + 1] = excl + c0;
        }
        __syncthreads();
        for (int j = t; j < n; j += 512) {       // place: node-sorted src list
            u32 e = ebuf[cs + j];
            int pos = atomicAdd(&lofs[e & 127], 1);
            sorted[pos] = (int)(e >> 7);
        }
        __syncthreads();
        // gather + accumulate (no atomics; sorted[] reads are wave-broadcast)
#pragma unroll
        for (int i = 0; i < 16; ++i) {
            int node = wave * 16 + i;
            int p = lstart[node], pe = p + lcnt[node];
            for (; p + 8 <= pe; p += 8) {        // 8 loads in flight
                int s[8];
#pragma unroll
                for (int k = 0; k < 8; ++k) s[k] = sorted[p + k];
                u32 w[8];
#pragma unroll
                for (int k = 0; k < 8; ++k) w[k] = Xu[(size_t)s[k] * 64 + lane];
#pragma unroll
                for (int k = 0; k < 8; ++k) {
                    a0[i] += bf2f((u16)w[k]);
                    a1[i] += bf2f((u16)(w[k] >> 16));
                }
            }
            for (; p < pe; ++p) {
                u32 w = Xu[(size_t)sorted[p] * 64 + lane];
                a0[i] += bf2f((u16)w);
                a1[i] += bf2f((u16)(w >> 16));
            }
        }
        __syncthreads();                         // protect lcnt/sorted for next chunk
    }

    u32* Tu = (u32*)T;
#pragma unroll
    for (int i = 0; i < 16; ++i) {
        int row = bkt * 128 + wave * 16 + i;
        Tu[(size_t)row * 64 + lane] = (u32)f2bf(a0[i]) | ((u32)f2bf(a1[i]) << 16);
    }
}

// ---------------- weight transpose + cast: Wt[n][k] = (bf16)W[k][n] ----------------
__global__ __launch_bounds__(256) void transpose_w(const float* a, const float* b,
                                                   const float* c, const float* d, u16* Wt) {
    const float* w = (blockIdx.x == 0) ? a : (blockIdx.x == 1) ? b : (blockIdx.x == 2) ? c : d;
    u16* o = Wt + blockIdx.x * 16384;
    for (int i = 0; i < 64; ++i) {
        int idx = threadIdx.x + i * 256;
        o[(idx & 127) * 128 + (idx >> 7)] = f2bf(w[idx]);
    }
}

// ---------------- fused GINConv MLP: C = relu(relu(A@W1+b1)@W2+b2) ----------------
// LDS: As (A tile -> h1 in place, wave-private rows) + Ws (W1 -> W2 in place).
// 52KB total -> 3 blocks/CU.
__global__ __launch_bounds__(256) void gemm2_relu(const u16* __restrict__ A,
                                                  const u16* __restrict__ Wt1,
                                                  const u16* __restrict__ Wt2,
                                                  const float* __restrict__ b1,
                                                  const float* __restrict__ b2,
                                                  u16* __restrict__ C) {
    __shared__ u16 As[64][136];     // A tile, then h1 (wave-private rows)
    __shared__ u16 Ws[128][136];    // W1, then W2
    int tid = threadIdx.x;
    size_t rowBase = (size_t)blockIdx.x * 64;

    // issue W2 global loads early; ds_write after gemm1 (overlap)
    uint4 w2r[8];
#pragma unroll
    for (int i = 0; i < 8; ++i) {
        int c = tid + i * 256;
        w2r[i] = *(const uint4*)(Wt2 + (c >> 4) * 128 + ((c & 15) << 3));
    }
    for (int i = 0; i < 4; ++i) {
        int c = tid + i * 256;
        int r = c >> 4, co = (c & 15) << 3;
        *(uint4*)&As[r][co] = *(const uint4*)(A + (rowBase + r) * 128 + co);
    }
    for (int i = 0; i < 8; ++i) {
        int c = tid + i * 256;
        int r = c >> 4, co = (c & 15) << 3;
        *(uint4*)&Ws[r][co] = *(const uint4*)(Wt1 + r * 128 + co);
    }
    __syncthreads();

    int lane = tid & 63, wave = tid >> 6;
    int quad = lane >> 4, l16 = lane & 15;

    f32x4 acc[8];
#pragma unroll
    for (int t = 0; t < 8; ++t) acc[t] = (f32x4){0.f, 0.f, 0.f, 0.f};
#pragma unroll
    for (int c = 0; c < 4; ++c) {
        short8 a = *(const short8*)&As[wave * 16 + l16][c * 32 + quad * 8];
#pragma unroll
        for (int t = 0; t < 8; ++t) {
            short8 b = *(const short8*)&Ws[t * 16 + l16][c * 32 + quad * 8];
            acc[t] = __builtin_amdgcn_mfma_f32_16x16x32_bf16(a, b, acc[t], 0, 0, 0);
        }
    }

    // h1 = relu(acc + b1) -> back into As (each wave touches only its 16 rows)
#pragma unroll
    for (int t = 0; t < 8; ++t) {
        int col = t * 16 + l16;
        float bv = b1[col];
#pragma unroll
        for (int r = 0; r < 4; ++r)
            As[wave * 16 + quad * 4 + r][col] = f2bf(fmaxf(acc[t][r] + bv, 0.f));
    }
    __syncthreads();                  // all waves done reading W1 (and their A rows)

    // overwrite Ws with W2 (registers already loaded)
#pragma unroll
    for (int i = 0; i < 8; ++i) {
        int c = tid + i * 256;
        *(uint4*)&Ws[c >> 4][(c & 15) << 3] = w2r[i];
    }
    __syncthreads();                  // Ws is now W2; As rows are wave-private h1

    f32x4 acc2[8];
#pragma unroll
    for (int t = 0; t < 8; ++t) acc2[t] = (f32x4){0.f, 0.f, 0.f, 0.f};
#pragma unroll
    for (int c = 0; c < 4; ++c) {
        short8 a = *(const short8*)&As[wave * 16 + l16][c * 32 + quad * 8];
#pragma unroll
        for (int t = 0; t < 8; ++t) {
            short8 b = *(const short8*)&Ws[t * 16 + l16][c * 32 + quad * 8];
            acc2[t] = __builtin_amdgcn_mfma_f32_16x16x32_bf16(a, b, acc2[t], 0, 0, 0);
        }
    }
#pragma unroll
    for (int t = 0; t < 8; ++t) {
        int col = t * 16 + l16;
        float bv = b2[col];
#pragma unroll
        for (int r = 0; r < 4; ++r) {
            int row = wave * 16 + quad * 4 + r;
            C[(rowBase + row) * 128 + col] = f2bf(fmaxf(acc2[t][r] + bv, 0.f));
        }
    }
}

// ---------------- normalize + per-node MLP (128->32->32->32), fp32 weights ----------------
__global__ __launch_bounds__(256) void norm_mlp(const u16* __restrict__ X,
                                                const float* Ws1, const float* bs1,
                                                const float* Ws2, const float* bs2,
                                                const float* Ws3, const float* bs3,
                                                float* __restrict__ S) {
    __shared__ float W1s[128 * 32];
    __shared__ float W2s[32 * 32];
    __shared__ float W3s[32 * 32];
    __shared__ float b1s[32], b2s[32], b3s[32];
    __shared__ float hbuf[4][128];
    __shared__ float sbuf[4][32];
    int t = threadIdx.x;
    for (int i = 0; i < 16; ++i) W1s[t + i * 256] = Ws1[t + i * 256];
    for (int i = 0; i < 4; ++i) { W2s[t + i * 256] = Ws2[t + i * 256]; W3s[t + i * 256] = Ws3[t + i * 256]; }
    if (t < 32) { b1s[t] = bs1[t]; b2s[t] = bs2[t]; b3s[t] = bs3[t]; }
    __syncthreads();

    int wave = t >> 6, lane = t & 63;
    int node = blockIdx.x * 4 + wave;
    u32 v = ((const u32*)X)[(size_t)node * 64 + lane];
    float f0 = bf2f((u16)v), f1 = bf2f((u16)(v >> 16));
    float ss = f0 * f0 + f1 * f1;
    for (int o = 1; o < 64; o <<= 1) ss += __shfl_xor(ss, o, 64);
    float inv = 1.0f / fmaxf(sqrtf(ss), 1e-12f);
    hbuf[wave][2 * lane] = f0 * inv;
    hbuf[wave][2 * lane + 1] = f1 * inv;
    __syncthreads();

    int j = lane & 31, half = lane >> 5;
    float p = 0.f;
    for (int i = 0; i < 64; ++i) { int k = half * 64 + i; p += hbuf[wave][k] * W1s[k * 32 + j]; }
    p += __shfl_xor(p, 32, 64);
    float s1 = fmaxf(p + b1s[j], 0.f);
    if (!half) sbuf[wave][j] = s1;
    __syncthreads();

    p = 0.f;
    for (int i = 0; i < 16; ++i) { int k = half * 16 + i; p += sbuf[wave][k] * W2s[k * 32 + j]; }
    p += __shfl_xor(p, 32, 64);
    float s2 = fmaxf(p + b2s[j], 0.f);
    __syncthreads();
    if (!half) sbuf[wave][j] = s2;
    __syncthreads();

    p = 0.f;
    for (int i = 0; i < 16; ++i) { int k = half * 16 + i; p += sbuf[wave][k] * W3s[k * 32 + j]; }
    p += __shfl_xor(p, 32, 64);
    float s3 = fmaxf(p + b3s[j], 0.f);
    if (!half) S[(size_t)node * 32 + j] = s3;
}

// ---------------- per-graph Gram: out[g][f][e] = sum_n S[g,n,f]*S[g,n,e] ----------------
__global__ __launch_bounds__(256) void gram(const float* __restrict__ S,
                                            float* __restrict__ out) {
    __shared__ float Sg[256 * 32];
    int t = threadIdx.x, g = blockIdx.x;
    const float4* src = (const float4*)(S + (size_t)g * 8192);
    float4* dst = (float4*)Sg;
    for (int i = 0; i < 8; ++i) dst[t + i * 256] = src[t + i * 256];
    __syncthreads();

    int f = t >> 3, e0 = (t & 7) << 2;
    float4 a = {0.f, 0.f, 0.f, 0.f};
    for (int n = 0; n < 256; ++n) {
        float sf = Sg[n * 32 + f];
        float4 se = *(const float4*)&Sg[n * 32 + e0];
        a.x += sf * se.x; a.y += sf * se.y; a.z += sf * se.z; a.w += sf * se.w;
    }
    *(float4*)(out + (size_t)g * 1024 + f * 32 + e0) = a;
}

// ---------------- per-graph MLP: 1024->32->32->2 (fp32) ----------------
__global__ __launch_bounds__(256) void graph_mlp(const float* __restrict__ HH,
                                                 const float* Wm1, const float* bm1,
                                                 const float* Wm2, const float* bm2,
                                                 const float* Wm3, const float* bm3,
                                                 float* __restrict__ out) {
    __shared__ float hh[1024];
    __shared__ float red[256];
    __shared__ float o1[32];
    __shared__ float o2[32];
    int t = threadIdx.x, g = blockIdx.x;
    ((float4*)hh)[t] = ((const float4*)(HH + (size_t)g * 1024))[t];
    __syncthreads();

    int j = t & 31, part = t >> 5;
    float p = 0.f;
    for (int i = 0; i < 128; ++i) { int k = part * 128 + i; p += hh[k] * Wm1[k * 32 + j]; }
    red[t] = p;
    __syncthreads();
    if (t < 32) {
        float s = 0.f;
        for (int q = 0; q < 8; ++q) s += red[q * 32 + t];
        o1[t] = fmaxf(s + bm1[t], 0.f);
    }
    __syncthreads();
    if (t < 32) {
        float s = 0.f;
        for (int k = 0; k < 32; ++k) s += o1[k] * Wm2[k * 32 + t];
        o2[t] = fmaxf(s + bm2[t], 0.f);
    }
    __syncthreads();
    if (t < 2) {
        float s = 0.f;
        for (int k = 0; k < 32; ++k) s += o2[k] * Wm3[k * 2 + t];
        out[524288 + g * 2 + t] = fmaxf(s + bm3[t], 0.f);
    }
}

// ---------------------------------------------------------------------------
extern "C" void kernel_launch(void* const* d_in, const int* in_sizes, int n_in,
                              void* d_out, int out_size, void* d_ws, size_t ws_size,
                              hipStream_t stream) {
    const float* x   = (const float*)d_in[0];
    const int*   ei  = (const int*)d_in[1];
    const float* W1a = (const float*)d_in[2];  const float* b1a = (const float*)d_in[3];
    const float* W2a = (const float*)d_in[4];  const float* b2a = (const float*)d_in[5];
    const float* W1b = (const float*)d_in[6];  const float* b1b = (const float*)d_in[7];
    const float* W2b = (const float*)d_in[8];  const float* b2b = (const float*)d_in[9];
    const float* Ws1 = (const float*)d_in[10]; const float* bs1 = (const float*)d_in[11];
    const float* Ws2 = (const float*)d_in[12]; const float* bs2 = (const float*)d_in[13];
    const float* Ws3 = (const float*)d_in[14]; const float* bs3 = (const float*)d_in[15];
    const float* Wm1 = (const float*)d_in[16]; const float* bm1 = (const float*)d_in[17];
    const float* Wm2 = (const float*)d_in[18]; const float* bm2 = (const float*)d_in[19];
    const float* Wm3 = (const float*)d_in[20]; const float* bm3 = (const float*)d_in[21];
    float* out = (float*)d_out;

    const int* gsrc = ei;
    const int* gdst = ei + NE;

    char* ws = (char*)d_ws;
    size_t off = 0;
    auto alloc = [&](size_t bytes) { size_t r = off; off = (off + bytes + 255) & ~(size_t)255; return r; };
    int*  cursor = (int*)(ws + alloc((size_t)NB * 4));
    u32*  ebuf   = (u32*)(ws + alloc((size_t)NB * BCAP * 4));   // 16 MB
    u16*  Wt     = (u16*)(ws + alloc(4 * 16384 * 2));
    u16*  X0     = (u16*)(ws + alloc((size_t)NN * 128 * 2));   // xb / hA / hB
    u16*  B1     = (u16*)(ws + alloc((size_t)NN * 128 * 2));   // aggregated T
    float* S     = (float*)B1;                                  // alias: B1 dead after last gemm2
    (void)ws_size; (void)n_in; (void)in_sizes; (void)out_size;

    // ---- edge binning: direct scatter into fixed bucket regions ----
    init_cursor<<<NB / 256, 256, 0, stream>>>(cursor);
    bin_scatter<<<NE / ECH, 256, 0, stream>>>(gsrc, gdst, cursor, ebuf);

    // ---- casts ----
    cast_x<<<NN * 128 / (256 * 8), 256, 0, stream>>>(x, X0);
    transpose_w<<<4, 256, 0, stream>>>(W1a, W2a, W1b, W2b, Wt);

    // ---- layer A ----
    aggregate_bucket<<<NB, 512, 0, stream>>>(X0, ebuf, cursor, B1);
    gemm2_relu<<<NN / 64, 256, 0, stream>>>(B1, Wt + 0 * 16384, Wt + 1 * 16384, b1a, b2a, X0);
    // ---- layer B ----
    aggregate_bucket<<<NB, 512, 0, stream>>>(X0, ebuf, cursor, B1);
    gemm2_relu<<<NN / 64, 256, 0, stream>>>(B1, Wt + 2 * 16384, Wt + 3 * 16384, b1b, b2b, X0);

    // ---- tail: normalize + node MLP (S aliases B1), Gram -> out, graph MLP ----
    norm_mlp<<<NN / 4, 256, 0, stream>>>(X0, Ws1, bs1, Ws2, bs2, Ws3, bs3, S);
    gram<<<NG, 256, 0, stream>>>(S, out);
    graph_mlp<<<NG, 256, 0, stream>>>(out, Wm1, bm1, Wm2, bm2, Wm3, bm3, out);
}

// Round 9
// 585.989 us; speedup vs baseline: 1.2624x; 1.1230x over previous
//
#include <hip/hip_runtime.h>
#include <hip/hip_bf16.h>

// ---------------------------------------------------------------------------
// GIN forward (all I/O fp32):
//   2x GINConv(128->128->128, eps=0) + ReLU, L2 row-normalize,
//   per-node MLP 128->32->32->32, per-graph Gram (32x32 -> 1024),
//   per-graph MLP 1024->32->32->2.
// Internals: node features bf16, fp32 accumulate.
// Binning: direct scatter into fixed 4096-capacity bucket regions.
// Aggregation: per-bucket LDS counting sort -> masked always-8-wide register
// gather (no serial remainder loop -> no pipeline drain at node boundaries).
// GINConv: fused 2-GEMM kernel; W2 reuses W1's LDS (52KB -> 3 blocks/CU).
// norm_mlp: 32 nodes/block (8x weight-staging amortization vs 4/block).
// ---------------------------------------------------------------------------

#define NN 131072      // nodes
#define NE 2097152     // edges
#define NG 512         // graphs
#define NB 1024        // buckets (128 nodes each)
#define BCAP 4096      // fixed ebuf capacity per bucket
#define ECH 8192       // edges per scatter block (NE/256)
#define CAP 3072       // edge-sort chunk capacity (bucket avg 2048, sigma ~45)

typedef unsigned short u16;
typedef unsigned int u32;
typedef __attribute__((ext_vector_type(8))) short short8;   // 8 x bf16
typedef __attribute__((ext_vector_type(4))) float f32x4;

__device__ __forceinline__ float bf2f(u16 u) {
    union { u32 i; float f; } x; x.i = ((u32)u) << 16; return x.f;
}
__device__ __forceinline__ u16 f2bf(float f) {
    union { u32 i; float f; } x; x.f = f;
    u32 r = x.i + 0x7fffu + ((x.i >> 16) & 1u);   // RNE
    return (u16)(r >> 16);
}

// ---------------- cast x: fp32 -> bf16 ----------------
__global__ __launch_bounds__(256) void cast_x(const float* __restrict__ xf,
                                              u16* __restrict__ xb) {
    int i = blockIdx.x * 256 + threadIdx.x;       // 8 floats per thread
    const float4* src = (const float4*)xf;
    float4 a = src[2 * i], b = src[2 * i + 1];
    uint4 o;
    o.x = (u32)f2bf(a.x) | ((u32)f2bf(a.y) << 16);
    o.y = (u32)f2bf(a.z) | ((u32)f2bf(a.w) << 16);
    o.z = (u32)f2bf(b.x) | ((u32)f2bf(b.y) << 16);
    o.w = (u32)f2bf(b.z) | ((u32)f2bf(b.w) << 16);
    ((uint4*)xb)[i] = o;
}

// ---------------- cursor init: cursor[b] = b * BCAP ----------------
__global__ __launch_bounds__(256) void init_cursor(int* __restrict__ cursor) {
    int b = blockIdx.x * 256 + threadIdx.x;
    cursor[b] = b * BCAP;
}

// ---------------- direct scatter into bucket regions ----------------
// ebuf[bucket region b*BCAP ...] = (src << 7) | (dst & 127)
__global__ __launch_bounds__(256) void bin_scatter(const int* __restrict__ gsrc,
                                                   const int* __restrict__ gdst,
                                                   int* __restrict__ cursor,
                                                   u32* __restrict__ ebuf) {
    __shared__ int lc[NB];   // local counts
    __shared__ int rb[NB];   // reserved run base (global)
    __shared__ int lb[NB];   // local bump
    int t = threadIdx.x;
    for (int i = 0; i < 4; ++i) lc[t + i * 256] = 0;
    __syncthreads();
    int base = blockIdx.x * ECH;
    for (int i = 0; i < ECH / 256; ++i) {
        int d = gdst[base + i * 256 + t];
        atomicAdd(&lc[d >> 7], 1);
    }
    __syncthreads();
    for (int i = 0; i < 4; ++i) {
        int b = t + i * 256;
        int c = lc[b];
        rb[b] = c ? atomicAdd(&cursor[b], c) : 0;
        lb[b] = 0;
    }
    __syncthreads();
    for (int i = 0; i < ECH / 256; ++i) {
        int idx = base + i * 256 + t;
        int d = gdst[idx];
        int s = gsrc[idx];
        int b = d >> 7;
        int o = atomicAdd(&lb[b], 1);
        ebuf[rb[b] + o] = ((u32)s << 7) | (u32)(d & 127);
    }
}

// ---------------- aggregation: T[i] = X[i] + sum_{j->i} X[j] ----------------
// Block = one bucket (128 nodes), 8 waves, 16 nodes/wave.
// Masked always-8-wide gather: every edge is in an 8-deep load pipeline;
// padding lanes re-load the last edge (same lines, L1-hit) with mask 0.
__global__ __launch_bounds__(512) void aggregate_bucket(const u16* __restrict__ X,
                                                        const u32* __restrict__ ebuf,
                                                        const int* __restrict__ bcur,
                                                        u16* __restrict__ T) {
    __shared__ int lcnt[128];
    __shared__ int lstart[128];
    __shared__ int lofs[128];
    __shared__ int sorted[CAP];
    int t = threadIdx.x, lane = t & 63, wave = t >> 6;   // 8 waves
    int bkt = blockIdx.x;
    const u32* Xu = (const u32*)X;

    // init register accumulators with own row (eps=0 self term)
    float a0[16], a1[16];
#pragma unroll
    for (int i = 0; i < 16; ++i) {
        int row = bkt * 128 + wave * 16 + i;
        u32 v = Xu[(size_t)row * 64 + lane];
        a0[i] = bf2f((u16)v);
        a1[i] = bf2f((u16)(v >> 16));
    }

    int e0 = bkt * BCAP, e1 = bcur[bkt];       // cursor holds base+count after scatter
    for (int cs = e0; cs < e1; cs += CAP) {
        int n = min(CAP, e1 - cs);
        if (t < 128) lcnt[t] = 0;
        __syncthreads();
        for (int j = t; j < n; j += 512)
            atomicAdd(&lcnt[ebuf[cs + j] & 127], 1);
        __syncthreads();
        if (wave == 0) {                         // exclusive scan of 128 counts
            int c0 = lcnt[2 * lane], c1 = lcnt[2 * lane + 1];
            int s = c0 + c1, e = s;
            for (int o = 1; o < 64; o <<= 1) {
                int u = __shfl_up(e, o, 64);
                if (lane >= o) e += u;
            }
            int excl = e - s;
            lstart[2 * lane] = excl;          lofs[2 * lane] = excl;
            lstart[2 * lane + 1] = excl + c0; lofs[2 * lane + 1] = excl + c0;
        }
        __syncthreads();
        for (int j = t; j < n; j += 512) {       // place: node-sorted src list
            u32 e = ebuf[cs + j];
            int pos = atomicAdd(&lofs[e & 127], 1);
            sorted[pos] = (int)(e >> 7);
        }
        __syncthreads();
        // gather + accumulate: always 8 loads in flight, masked tail
#pragma unroll
        for (int i = 0; i < 16; ++i) {
            int node = wave * 16 + i;
            int p = lstart[node], pe = p + lcnt[node];
            for (; p < pe; p += 8) {
                int s[8]; float m[8];
#pragma unroll
                for (int k = 0; k < 8; ++k) {
                    int q = p + k;
                    s[k] = sorted[q < pe ? q : pe - 1];
                    m[k] = (q < pe) ? 1.f : 0.f;
                }
                u32 w[8];
#pragma unroll
                for (int k = 0; k < 8; ++k) w[k] = Xu[(size_t)s[k] * 64 + lane];
#pragma unroll
                for (int k = 0; k < 8; ++k) {
                    a0[i] = fmaf(m[k], bf2f((u16)w[k]), a0[i]);
                    a1[i] = fmaf(m[k], bf2f((u16)(w[k] >> 16)), a1[i]);
                }
            }
        }
        __syncthreads();                         // protect lcnt/sorted for next chunk
    }

    u32* Tu = (u32*)T;
#pragma unroll
    for (int i = 0; i < 16; ++i) {
        int row = bkt * 128 + wave * 16 + i;
        Tu[(size_t)row * 64 + lane] = (u32)f2bf(a0[i]) | ((u32)f2bf(a1[i]) << 16);
    }
}

// ---------------- weight transpose + cast: Wt[n][k] = (bf16)W[k][n] ----------------
__global__ __launch_bounds__(256) void transpose_w(const float* a, const float* b,
                                                   const float* c, const float* d, u16* Wt) {
    const float* w = (blockIdx.x == 0) ? a : (blockIdx.x == 1) ? b : (blockIdx.x == 2) ? c : d;
    u16* o = Wt + blockIdx.x * 16384;
    for (int i = 0; i < 64; ++i) {
        int idx = threadIdx.x + i * 256;
        o[(idx & 127) * 128 + (idx >> 7)] = f2bf(w[idx]);
    }
}

// ---------------- fused GINConv MLP: C = relu(relu(A@W1+b1)@W2+b2) ----------------
// LDS: As (A tile -> h1 in place, wave-private rows) + Ws (W1 -> W2 in place).
// 52KB total -> 3 blocks/CU.
__global__ __launch_bounds__(256) void gemm2_relu(const u16* __restrict__ A,
                                                  const u16* __restrict__ Wt1,
                                                  const u16* __restrict__ Wt2,
                                                  const float* __restrict__ b1,
                                                  const float* __restrict__ b2,
                                                  u16* __restrict__ C) {
    __shared__ u16 As[64][136];     // A tile, then h1 (wave-private rows)
    __shared__ u16 Ws[128][136];    // W1, then W2
    int tid = threadIdx.x;
    size_t rowBase = (size_t)blockIdx.x * 64;

    // issue W2 global loads early; ds_write after gemm1 (overlap)
    uint4 w2r[8];
#pragma unroll
    for (int i = 0; i < 8; ++i) {
        int c = tid + i * 256;
        w2r[i] = *(const uint4*)(Wt2 + (c >> 4) * 128 + ((c & 15) << 3));
    }
    for (int i = 0; i < 4; ++i) {
        int c = tid + i * 256;
        int r = c >> 4, co = (c & 15) << 3;
        *(uint4*)&As[r][co] = *(const uint4*)(A + (rowBase + r) * 128 + co);
    }
    for (int i = 0; i < 8; ++i) {
        int c = tid + i * 256;
        int r = c >> 4, co = (c & 15) << 3;
        *(uint4*)&Ws[r][co] = *(const uint4*)(Wt1 + r * 128 + co);
    }
    __syncthreads();

    int lane = tid & 63, wave = tid >> 6;
    int quad = lane >> 4, l16 = lane & 15;

    f32x4 acc[8];
#pragma unroll
    for (int t = 0; t < 8; ++t) acc[t] = (f32x4){0.f, 0.f, 0.f, 0.f};
#pragma unroll
    for (int c = 0; c < 4; ++c) {
        short8 a = *(const short8*)&As[wave * 16 + l16][c * 32 + quad * 8];
#pragma unroll
        for (int t = 0; t < 8; ++t) {
            short8 b = *(const short8*)&Ws[t * 16 + l16][c * 32 + quad * 8];
            acc[t] = __builtin_amdgcn_mfma_f32_16x16x32_bf16(a, b, acc[t], 0, 0, 0);
        }
    }

    // h1 = relu(acc + b1) -> back into As (each wave touches only its 16 rows)
#pragma unroll
    for (int t = 0; t < 8; ++t) {
        int col = t * 16 + l16;
        float bv = b1[col];
#pragma unroll
        for (int r = 0; r < 4; ++r)
            As[wave * 16 + quad * 4 + r][col] = f2bf(fmaxf(acc[t][r] + bv, 0.f));
    }
    __syncthreads();                  // all waves done reading W1 (and their A rows)

    // overwrite Ws with W2 (registers already loaded)
#pragma unroll
    for (int i = 0; i < 8; ++i) {
        int c = tid + i * 256;
        *(uint4*)&Ws[c >> 4][(c & 15) << 3] = w2r[i];
    }
    __syncthreads();                  // Ws is now W2; As rows are wave-private h1

    f32x4 acc2[8];
#pragma unroll
    for (int t = 0; t < 8; ++t) acc2[t] = (f32x4){0.f, 0.f, 0.f, 0.f};
#pragma unroll
    for (int c = 0; c < 4; ++c) {
        short8 a = *(const short8*)&As[wave * 16 + l16][c * 32 + quad * 8];
#pragma unroll
        for (int t = 0; t < 8; ++t) {
            short8 b = *(const short8*)&Ws[t * 16 + l16][c * 32 + quad * 8];
            acc2[t] = __builtin_amdgcn_mfma_f32_16x16x32_bf16(a, b, acc2[t], 0, 0, 0);
        }
    }
#pragma unroll
    for (int t = 0; t < 8; ++t) {
        int col = t * 16 + l16;
        float bv = b2[col];
#pragma unroll
        for (int r = 0; r < 4; ++r) {
            int row = wave * 16 + quad * 4 + r;
            C[(rowBase + row) * 128 + col] = f2bf(fmaxf(acc2[t][r] + bv, 0.f));
        }
    }
}

// ---------------- normalize + per-node MLP (128->32->32->32), fp32 weights ----------------
// 32 nodes per block (4 waves x 8-node loop): 8x weight-staging amortization.
__global__ __launch_bounds__(256) void norm_mlp(const u16* __restrict__ X,
                                                const float* Ws1, const float* bs1,
                                                const float* Ws2, const float* bs2,
                                                const float* Ws3, const float* bs3,
                                                float* __restrict__ S) {
    __shared__ float W1s[128 * 32];
    __shared__ float W2s[32 * 32];
    __shared__ float W3s[32 * 32];
    __shared__ float b1s[32], b2s[32], b3s[32];
    __shared__ float hbuf[4][128];
    __shared__ float sbuf[4][32];
    int t = threadIdx.x;
    for (int i = 0; i < 16; ++i) W1s[t + i * 256] = Ws1[t + i * 256];
    for (int i = 0; i < 4; ++i) { W2s[t + i * 256] = Ws2[t + i * 256]; W3s[t + i * 256] = Ws3[t + i * 256]; }
    if (t < 32) { b1s[t] = bs1[t]; b2s[t] = bs2[t]; b3s[t] = bs3[t]; }
    __syncthreads();

    int wave = t >> 6, lane = t & 63;
    int j = lane & 31, half = lane >> 5;

    for (int it = 0; it < 8; ++it) {
        int node = blockIdx.x * 32 + wave * 8 + it;
        u32 v = ((const u32*)X)[(size_t)node * 64 + lane];
        float f0 = bf2f((u16)v), f1 = bf2f((u16)(v >> 16));
        float ss = f0 * f0 + f1 * f1;
        for (int o = 1; o < 64; o <<= 1) ss += __shfl_xor(ss, o, 64);
        float inv = 1.0f / fmaxf(sqrtf(ss), 1e-12f);
        hbuf[wave][2 * lane] = f0 * inv;
        hbuf[wave][2 * lane + 1] = f1 * inv;
        __syncthreads();

        float p = 0.f;
        for (int i = 0; i < 64; ++i) { int k = half * 64 + i; p += hbuf[wave][k] * W1s[k * 32 + j]; }
        p += __shfl_xor(p, 32, 64);
        float s1 = fmaxf(p + b1s[j], 0.f);
        if (!half) sbuf[wave][j] = s1;
        __syncthreads();

        p = 0.f;
        for (int i = 0; i < 16; ++i) { int k = half * 16 + i; p += sbuf[wave][k] * W2s[k * 32 + j]; }
        p += __shfl_xor(p, 32, 64);
        float s2 = fmaxf(p + b2s[j], 0.f);
        __syncthreads();
        if (!half) sbuf[wave][j] = s2;
        __syncthreads();

        p = 0.f;
        for (int i = 0; i < 16; ++i) { int k = half * 16 + i; p += sbuf[wave][k] * W3s[k * 32 + j]; }
        p += __shfl_xor(p, 32, 64);
        float s3 = fmaxf(p + b3s[j], 0.f);
        if (!half) S[(size_t)node * 32 + j] = s3;
        __syncthreads();
    }
}

// ---------------- per-graph Gram: out[g][f][e] = sum_n S[g,n,f]*S[g,n,e] ----------------
__global__ __launch_bounds__(256) void gram(const float* __restrict__ S,
                                            float* __restrict__ out) {
    __shared__ float Sg[256 * 32];
    int t = threadIdx.x, g = blockIdx.x;
    const float4* src = (const float4*)(S + (size_t)g * 8192);
    float4* dst = (float4*)Sg;
    for (int i = 0; i < 8; ++i) dst[t + i * 256] = src[t + i * 256];
    __syncthreads();

    int f = t >> 3, e0 = (t & 7) << 2;
    float4 a = {0.f, 0.f, 0.f, 0.f};
    for (int n = 0; n < 256; ++n) {
        float sf = Sg[n * 32 + f];
        float4 se = *(const float4*)&Sg[n * 32 + e0];
        a.x += sf * se.x; a.y += sf * se.y; a.z += sf * se.z; a.w += sf * se.w;
    }
    *(float4*)(out + (size_t)g * 1024 + f * 32 + e0) = a;
}

// ---------------- per-graph MLP: 1024->32->32->2 (fp32) ----------------
__global__ __launch_bounds__(256) void graph_mlp(const float* __restrict__ HH,
                                                 const float* Wm1, const float* bm1,
                                                 const float* Wm2, const float* bm2,
                                                 const float* Wm3, const float* bm3,
                                                 float* __restrict__ out) {
    __shared__ float hh[1024];
    __shared__ float red[256];
    __shared__ float o1[32];
    __shared__ float o2[32];
    int t = threadIdx.x, g = blockIdx.x;
    ((float4*)hh)[t] = ((const float4*)(HH + (size_t)g * 1024))[t];
    __syncthreads();

    int j = t & 31, part = t >> 5;
    float p = 0.f;
    for (int i = 0; i < 128; ++i) { int k = part * 128 + i; p += hh[k] * Wm1[k * 32 + j]; }
    red[t] = p;
    __syncthreads();
    if (t < 32) {
        float s = 0.f;
        for (int q = 0; q < 8; ++q) s += red[q * 32 + t];
        o1[t] = fmaxf(s + bm1[t], 0.f);
    }
    __syncthreads();
    if (t < 32) {
        float s = 0.f;
        for (int k = 0; k < 32; ++k) s += o1[k] * Wm2[k * 32 + t];
        o2[t] = fmaxf(s + bm2[t], 0.f);
    }
    __syncthreads();
    if (t < 2) {
        float s = 0.f;
        for (int k = 0; k < 32; ++k) s += o2[k] * Wm3[k * 2 + t];
        out[524288 + g * 2 + t] = fmaxf(s + bm3[t], 0.f);
    }
}

// ---------------------------------------------------------------------------
extern "C" void kernel_launch(void* const* d_in, const int* in_sizes, int n_in,
                              void* d_out, int out_size, void* d_ws, size_t ws_size,
                              hipStream_t stream) {
    const float* x   = (const float*)d_in[0];
    const int*   ei  = (const int*)d_in[1];
    const float* W1a = (const float*)d_in[2];  const float* b1a = (const float*)d_in[3];
    const float* W2a = (const float*)d_in[4];  const float* b2a = (const float*)d_in[5];
    const float* W1b = (const float*)d_in[6];  const float* b1b = (const float*)d_in[7];
    const float* W2b = (const float*)d_in[8];  const float* b2b = (const float*)d_in[9];
    const float* Ws1 = (const float*)d_in[10]; const float* bs1 = (const float*)d_in[11];
    const float* Ws2 = (const float*)d_in[12]; const float* bs2 = (const float*)d_in[13];
    const float* Ws3 = (const float*)d_in[14]; const float* bs3 = (const float*)d_in[15];
    const float* Wm1 = (const float*)d_in[16]; const float* bm1 = (const float*)d_in[17];
    const float* Wm2 = (const float*)d_in[18]; const float* bm2 = (const float*)d_in[19];
    const float* Wm3 = (const float*)d_in[20]; const float* bm3 = (const float*)d_in[21];
    float* out = (float*)d_out;

    const int* gsrc = ei;
    const int* gdst = ei + NE;

    char* ws = (char*)d_ws;
    size_t off = 0;
    auto alloc = [&](size_t bytes) { size_t r = off; off = (off + bytes + 255) & ~(size_t)255; return r; };
    int*  cursor = (int*)(ws + alloc((size_t)NB * 4));
    u32*  ebuf   = (u32*)(ws + alloc((size_t)NB * BCAP * 4));   // 16 MB
    u16*  Wt     = (u16*)(ws + alloc(4 * 16384 * 2));
    u16*  X0     = (u16*)(ws + alloc((size_t)NN * 128 * 2));   // xb / hA / hB
    u16*  B1     = (u16*)(ws + alloc((size_t)NN * 128 * 2));   // aggregated T
    float* S     = (float*)B1;                                  // alias: B1 dead after last gemm2
    (void)ws_size; (void)n_in; (void)in_sizes; (void)out_size;

    // ---- edge binning: direct scatter into fixed bucket regions ----
    init_cursor<<<NB / 256, 256, 0, stream>>>(cursor);
    bin_scatter<<<NE / ECH, 256, 0, stream>>>(gsrc, gdst, cursor, ebuf);

    // ---- casts ----
    cast_x<<<NN * 128 / (256 * 8), 256, 0, stream>>>(x, X0);
    transpose_w<<<4, 256, 0, stream>>>(W1a, W2a, W1b, W2b, Wt);

    // ---- layer A ----
    aggregate_bucket<<<NB, 512, 0, stream>>>(X0, ebuf, cursor, B1);
    gemm2_relu<<<NN / 64, 256, 0, stream>>>(B1, Wt + 0 * 16384, Wt + 1 * 16384, b1a, b2a, X0);
    // ---- layer B ----
    aggregate_bucket<<<NB, 512, 0, stream>>>(X0, ebuf, cursor, B1);
    gemm2_relu<<<NN / 64, 256, 0, stream>>>(B1, Wt + 2 * 16384, Wt + 3 * 16384, b1b, b2b, X0);

    // ---- tail: normalize + node MLP (S aliases B1), Gram -> out, graph MLP ----
    norm_mlp<<<NN / 32, 256, 0, stream>>>(X0, Ws1, bs1, Ws2, bs2, Ws3, bs3, S);
    gram<<<NG, 256, 0, stream>>>(S, out);
    graph_mlp<<<NG, 256, 0, stream>>>(out, Wm1, bm1, Wm2, bm2, Wm3, bm3, out);
}

// Round 10
// 502.722 us; speedup vs baseline: 1.4715x; 1.1656x over previous
//
#include <hip/hip_runtime.h>
#include <hip/hip_bf16.h>

// ---------------------------------------------------------------------------
// GIN forward (all I/O fp32):
//   2x GINConv(128->128->128, eps=0) + ReLU, L2 row-normalize,
//   per-node MLP 128->32->32->32, per-graph Gram (32x32 -> 1024),
//   per-graph MLP 1024->32->32->2.
// Internals: node features bf16, fp32 accumulate.
// Binning: direct scatter into fixed 4096-capacity bucket regions.
// Aggregation: per-bucket LDS counting sort -> masked always-8-wide gather.
// GINConv: fused 2-GEMM kernel; W2 reuses W1's LDS (52KB -> 3 blocks/CU).
// Node MLP: MFMA-based (64 nodes/block) -- replaces 117us serial-VALU GEMV.
// ---------------------------------------------------------------------------

#define NN 131072      // nodes
#define NE 2097152     // edges
#define NG 512         // graphs
#define NB 1024        // buckets (128 nodes each)
#define BCAP 4096      // fixed ebuf capacity per bucket
#define ECH 8192       // edges per scatter block (NE/256)
#define CAP 3072       // edge-sort chunk capacity (bucket avg 2048, sigma ~45)

typedef unsigned short u16;
typedef unsigned int u32;
typedef __attribute__((ext_vector_type(8))) short short8;   // 8 x bf16
typedef __attribute__((ext_vector_type(4))) float f32x4;

__device__ __forceinline__ float bf2f(u16 u) {
    union { u32 i; float f; } x; x.i = ((u32)u) << 16; return x.f;
}
__device__ __forceinline__ u16 f2bf(float f) {
    union { u32 i; float f; } x; x.f = f;
    u32 r = x.i + 0x7fffu + ((x.i >> 16) & 1u);   // RNE
    return (u16)(r >> 16);
}

// ---------------- cast x: fp32 -> bf16 ----------------
__global__ __launch_bounds__(256) void cast_x(const float* __restrict__ xf,
                                              u16* __restrict__ xb) {
    int i = blockIdx.x * 256 + threadIdx.x;       // 8 floats per thread
    const float4* src = (const float4*)xf;
    float4 a = src[2 * i], b = src[2 * i + 1];
    uint4 o;
    o.x = (u32)f2bf(a.x) | ((u32)f2bf(a.y) << 16);
    o.y = (u32)f2bf(a.z) | ((u32)f2bf(a.w) << 16);
    o.z = (u32)f2bf(b.x) | ((u32)f2bf(b.y) << 16);
    o.w = (u32)f2bf(b.z) | ((u32)f2bf(b.w) << 16);
    ((uint4*)xb)[i] = o;
}

// ---------------- cursor init: cursor[b] = b * BCAP ----------------
__global__ __launch_bounds__(256) void init_cursor(int* __restrict__ cursor) {
    int b = blockIdx.x * 256 + threadIdx.x;
    cursor[b] = b * BCAP;
}

// ---------------- direct scatter into bucket regions ----------------
// ebuf[bucket region b*BCAP ...] = (src << 7) | (dst & 127)
__global__ __launch_bounds__(256) void bin_scatter(const int* __restrict__ gsrc,
                                                   const int* __restrict__ gdst,
                                                   int* __restrict__ cursor,
                                                   u32* __restrict__ ebuf) {
    __shared__ int lc[NB];   // local counts
    __shared__ int rb[NB];   // reserved run base (global)
    __shared__ int lb[NB];   // local bump
    int t = threadIdx.x;
    for (int i = 0; i < 4; ++i) lc[t + i * 256] = 0;
    __syncthreads();
    int base = blockIdx.x * ECH;
    for (int i = 0; i < ECH / 256; ++i) {
        int d = gdst[base + i * 256 + t];
        atomicAdd(&lc[d >> 7], 1);
    }
    __syncthreads();
    for (int i = 0; i < 4; ++i) {
        int b = t + i * 256;
        int c = lc[b];
        rb[b] = c ? atomicAdd(&cursor[b], c) : 0;
        lb[b] = 0;
    }
    __syncthreads();
    for (int i = 0; i < ECH / 256; ++i) {
        int idx = base + i * 256 + t;
        int d = gdst[idx];
        int s = gsrc[idx];
        int b = d >> 7;
        int o = atomicAdd(&lb[b], 1);
        ebuf[rb[b] + o] = ((u32)s << 7) | (u32)(d & 127);
    }
}

// ---------------- aggregation: T[i] = X[i] + sum_{j->i} X[j] ----------------
// Block = one bucket (128 nodes), 8 waves, 16 nodes/wave.
// Masked always-8-wide gather: every edge is in an 8-deep load pipeline.
__global__ __launch_bounds__(512) void aggregate_bucket(const u16* __restrict__ X,
                                                        const u32* __restrict__ ebuf,
                                                        const int* __restrict__ bcur,
                                                        u16* __restrict__ T) {
    __shared__ int lcnt[128];
    __shared__ int lstart[128];
    __shared__ int lofs[128];
    __shared__ int sorted[CAP];
    int t = threadIdx.x, lane = t & 63, wave = t >> 6;   // 8 waves
    int bkt = blockIdx.x;
    const u32* Xu = (const u32*)X;

    // init register accumulators with own row (eps=0 self term)
    float a0[16], a1[16];
#pragma unroll
    for (int i = 0; i < 16; ++i) {
        int row = bkt * 128 + wave * 16 + i;
        u32 v = Xu[(size_t)row * 64 + lane];
        a0[i] = bf2f((u16)v);
        a1[i] = bf2f((u16)(v >> 16));
    }

    int e0 = bkt * BCAP, e1 = bcur[bkt];       // cursor holds base+count after scatter
    for (int cs = e0; cs < e1; cs += CAP) {
        int n = min(CAP, e1 - cs);
        if (t < 128) lcnt[t] = 0;
        __syncthreads();
        for (int j = t; j < n; j += 512)
            atomicAdd(&lcnt[ebuf[cs + j] & 127], 1);
        __syncthreads();
        if (wave == 0) {                         // exclusive scan of 128 counts
            int c0 = lcnt[2 * lane], c1 = lcnt[2 * lane + 1];
            int s = c0 + c1, e = s;
            for (int o = 1; o < 64; o <<= 1) {
                int u = __shfl_up(e, o, 64);
                if (lane >= o) e += u;
            }
            int excl = e - s;
            lstart[2 * lane] = excl;          lofs[2 * lane] = excl;
            lstart[2 * lane + 1] = excl + c0; lofs[2 * lane + 1] = excl + c0;
        }
        __syncthreads();
        for (int j = t; j < n; j += 512) {       // place: node-sorted src list
            u32 e = ebuf[cs + j];
            int pos = atomicAdd(&lofs[e & 127], 1);
            sorted[pos] = (int)(e >> 7);
        }
        __syncthreads();
        // gather + accumulate: always 8 loads in flight, masked tail
#pragma unroll
        for (int i = 0; i < 16; ++i) {
            int node = wave * 16 + i;
            int p = lstart[node], pe = p + lcnt[node];
            for (; p < pe; p += 8) {
                int s[8]; float m[8];
#pragma unroll
                for (int k = 0; k < 8; ++k) {
                    int q = p + k;
                    s[k] = sorted[q < pe ? q : pe - 1];
                    m[k] = (q < pe) ? 1.f : 0.f;
                }
                u32 w[8];
#pragma unroll
                for (int k = 0; k < 8; ++k) w[k] = Xu[(size_t)s[k] * 64 + lane];
#pragma unroll
                for (int k = 0; k < 8; ++k) {
                    a0[i] = fmaf(m[k], bf2f((u16)w[k]), a0[i]);
                    a1[i] = fmaf(m[k], bf2f((u16)(w[k] >> 16)), a1[i]);
                }
            }
        }
        __syncthreads();                         // protect lcnt/sorted for next chunk
    }

    u32* Tu = (u32*)T;
#pragma unroll
    for (int i = 0; i < 16; ++i) {
        int row = bkt * 128 + wave * 16 + i;
        Tu[(size_t)row * 64 + lane] = (u32)f2bf(a0[i]) | ((u32)f2bf(a1[i]) << 16);
    }
}

// ---------------- weight transpose + cast: Wt[n][k] = (bf16)W[k][n] ----------------
__global__ __launch_bounds__(256) void transpose_w(const float* a, const float* b,
                                                   const float* c, const float* d, u16* Wt) {
    const float* w = (blockIdx.x == 0) ? a : (blockIdx.x == 1) ? b : (blockIdx.x == 2) ? c : d;
    u16* o = Wt + blockIdx.x * 16384;
    for (int i = 0; i < 64; ++i) {
        int idx = threadIdx.x + i * 256;
        o[(idx & 127) * 128 + (idx >> 7)] = f2bf(w[idx]);
    }
}

// ---------------- small-MLP weight transpose: n-major bf16 ----------------
// Wsm layout: [0:4096) Ws1t (32x128), [4096:5120) Ws2t (32x32), [5120:6144) Ws3t
__global__ __launch_bounds__(256) void transpose_small(const float* Ws1, const float* Ws2,
                                                       const float* Ws3, u16* Wsm) {
    int t = threadIdx.x;
    for (int i = 0; i < 16; ++i) {
        int idx = t + i * 256;               // over 4096; W1[k][n], k<128,n<32
        int k = idx >> 5, n = idx & 31;
        Wsm[n * 128 + k] = f2bf(Ws1[idx]);
    }
    for (int i = 0; i < 4; ++i) {
        int idx = t + i * 256;               // over 1024
        int k = idx >> 5, n = idx & 31;
        Wsm[4096 + n * 32 + k] = f2bf(Ws2[idx]);
        Wsm[5120 + n * 32 + k] = f2bf(Ws3[idx]);
    }
}

// ---------------- fused GINConv MLP: C = relu(relu(A@W1+b1)@W2+b2) ----------------
// LDS: As (A tile -> h1 in place, wave-private rows) + Ws (W1 -> W2 in place).
__global__ __launch_bounds__(256) void gemm2_relu(const u16* __restrict__ A,
                                                  const u16* __restrict__ Wt1,
                                                  const u16* __restrict__ Wt2,
                                                  const float* __restrict__ b1,
                                                  const float* __restrict__ b2,
                                                  u16* __restrict__ C) {
    __shared__ u16 As[64][136];     // A tile, then h1 (wave-private rows)
    __shared__ u16 Ws[128][136];    // W1, then W2
    int tid = threadIdx.x;
    size_t rowBase = (size_t)blockIdx.x * 64;

    // issue W2 global loads early; ds_write after gemm1 (overlap)
    uint4 w2r[8];
#pragma unroll
    for (int i = 0; i < 8; ++i) {
        int c = tid + i * 256;
        w2r[i] = *(const uint4*)(Wt2 + (c >> 4) * 128 + ((c & 15) << 3));
    }
    for (int i = 0; i < 4; ++i) {
        int c = tid + i * 256;
        int r = c >> 4, co = (c & 15) << 3;
        *(uint4*)&As[r][co] = *(const uint4*)(A + (rowBase + r) * 128 + co);
    }
    for (int i = 0; i < 8; ++i) {
        int c = tid + i * 256;
        int r = c >> 4, co = (c & 15) << 3;
        *(uint4*)&Ws[r][co] = *(const uint4*)(Wt1 + r * 128 + co);
    }
    __syncthreads();

    int lane = tid & 63, wave = tid >> 6;
    int quad = lane >> 4, l16 = lane & 15;

    f32x4 acc[8];
#pragma unroll
    for (int t = 0; t < 8; ++t) acc[t] = (f32x4){0.f, 0.f, 0.f, 0.f};
#pragma unroll
    for (int c = 0; c < 4; ++c) {
        short8 a = *(const short8*)&As[wave * 16 + l16][c * 32 + quad * 8];
#pragma unroll
        for (int t = 0; t < 8; ++t) {
            short8 b = *(const short8*)&Ws[t * 16 + l16][c * 32 + quad * 8];
            acc[t] = __builtin_amdgcn_mfma_f32_16x16x32_bf16(a, b, acc[t], 0, 0, 0);
        }
    }

    // h1 = relu(acc + b1) -> back into As (each wave touches only its 16 rows)
#pragma unroll
    for (int t = 0; t < 8; ++t) {
        int col = t * 16 + l16;
        float bv = b1[col];
#pragma unroll
        for (int r = 0; r < 4; ++r)
            As[wave * 16 + quad * 4 + r][col] = f2bf(fmaxf(acc[t][r] + bv, 0.f));
    }
    __syncthreads();                  // all waves done reading W1 (and their A rows)

    // overwrite Ws with W2 (registers already loaded)
#pragma unroll
    for (int i = 0; i < 8; ++i) {
        int c = tid + i * 256;
        *(uint4*)&Ws[c >> 4][(c & 15) << 3] = w2r[i];
    }
    __syncthreads();                  // Ws is now W2; As rows are wave-private h1

    f32x4 acc2[8];
#pragma unroll
    for (int t = 0; t < 8; ++t) acc2[t] = (f32x4){0.f, 0.f, 0.f, 0.f};
#pragma unroll
    for (int c = 0; c < 4; ++c) {
        short8 a = *(const short8*)&As[wave * 16 + l16][c * 32 + quad * 8];
#pragma unroll
        for (int t = 0; t < 8; ++t) {
            short8 b = *(const short8*)&Ws[t * 16 + l16][c * 32 + quad * 8];
            acc2[t] = __builtin_amdgcn_mfma_f32_16x16x32_bf16(a, b, acc2[t], 0, 0, 0);
        }
    }
#pragma unroll
    for (int t = 0; t < 8; ++t) {
        int col = t * 16 + l16;
        float bv = b2[col];
#pragma unroll
        for (int r = 0; r < 4; ++r) {
            int row = wave * 16 + quad * 4 + r;
            C[(rowBase + row) * 128 + col] = f2bf(fmaxf(acc2[t][r] + bv, 0.f));
        }
    }
}

// ---------------- MFMA node MLP: normalize + 128->32->32->32 ----------------
// Block = 64 nodes, 256 threads (4 waves x 16-row strips). All GEMVs as MFMA.
__global__ __launch_bounds__(256) void norm_mlp_mfma(const u16* __restrict__ X,
                                                     const u16* __restrict__ Wsm,
                                                     const float* __restrict__ bs1,
                                                     const float* __restrict__ bs2,
                                                     const float* __restrict__ bs3,
                                                     float* __restrict__ S) {
    __shared__ u16 As[64][136];      // normalized rows (bf16)
    __shared__ u16 W1s[32][136];     // Ws1t 32x128
    __shared__ u16 W23s[2][32][40];  // Ws2t, Ws3t 32x32
    __shared__ u16 H[64][40];        // hidden (wave-private 16-row strips)
    int tid = threadIdx.x, lane = tid & 63, wave = tid >> 6;
    int quad = lane >> 4, l16 = lane & 15;
    size_t rowBase = (size_t)blockIdx.x * 64;

    // stage weights (block-cooperative)
#pragma unroll
    for (int i = 0; i < 2; ++i) {
        int c = tid + i * 256;               // 512 chunks of 8 over 32x128
        int r = c >> 4, co = (c & 15) << 3;
        *(uint4*)&W1s[r][co] = *(const uint4*)(Wsm + r * 128 + co);
    }
    {
        int which = tid >> 7, cc = tid & 127;   // 128 chunks each for W2t/W3t
        int r = cc >> 2, co = (cc & 3) << 3;
        *(uint4*)&W23s[which][r][co] = *(const uint4*)(Wsm + 4096 + which * 1024 + r * 32 + co);
    }

    // normalize: each wave handles its 16 rows
    const u32* Xu = (const u32*)X;
    for (int i = 0; i < 16; ++i) {
        int row = wave * 16 + i;
        u32 v = Xu[(rowBase + row) * 64 + lane];
        float f0 = bf2f((u16)v), f1 = bf2f((u16)(v >> 16));
        float ss = f0 * f0 + f1 * f1;
        for (int o = 1; o < 64; o <<= 1) ss += __shfl_xor(ss, o, 64);
        float inv = 1.0f / fmaxf(sqrtf(ss), 1e-12f);
        *(u32*)&As[row][2 * lane] = (u32)f2bf(f0 * inv) | ((u32)f2bf(f1 * inv) << 16);
    }
    __syncthreads();

    // layer1: [64x128] @ [128x32] -- 2 N-tiles x 4 K-steps
    f32x4 acc[2];
    acc[0] = (f32x4){0.f, 0.f, 0.f, 0.f};
    acc[1] = (f32x4){0.f, 0.f, 0.f, 0.f};
#pragma unroll
    for (int c = 0; c < 4; ++c) {
        short8 a = *(const short8*)&As[wave * 16 + l16][c * 32 + quad * 8];
#pragma unroll
        for (int t = 0; t < 2; ++t) {
            short8 b = *(const short8*)&W1s[t * 16 + l16][c * 32 + quad * 8];
            acc[t] = __builtin_amdgcn_mfma_f32_16x16x32_bf16(a, b, acc[t], 0, 0, 0);
        }
    }
#pragma unroll
    for (int t = 0; t < 2; ++t) {
        int col = t * 16 + l16;
        float bv = bs1[col];
#pragma unroll
        for (int r = 0; r < 4; ++r)
            H[wave * 16 + quad * 4 + r][col] = f2bf(fmaxf(acc[t][r] + bv, 0.f));
    }
    __syncthreads();

    // layer2: [64x32] @ [32x32] -- K=32, one step
    f32x4 acc2[2];
    acc2[0] = (f32x4){0.f, 0.f, 0.f, 0.f};
    acc2[1] = (f32x4){0.f, 0.f, 0.f, 0.f};
    {
        short8 a = *(const short8*)&H[wave * 16 + l16][quad * 8];
#pragma unroll
        for (int t = 0; t < 2; ++t) {
            short8 b = *(const short8*)&W23s[0][t * 16 + l16][quad * 8];
            acc2[t] = __builtin_amdgcn_mfma_f32_16x16x32_bf16(a, b, acc2[t], 0, 0, 0);
        }
    }
    __syncthreads();
#pragma unroll
    for (int t = 0; t < 2; ++t) {
        int col = t * 16 + l16;
        float bv = bs2[col];
#pragma unroll
        for (int r = 0; r < 4; ++r)
            H[wave * 16 + quad * 4 + r][col] = f2bf(fmaxf(acc2[t][r] + bv, 0.f));
    }
    __syncthreads();

    // layer3: [64x32] @ [32x32] -> S (fp32 global)
    f32x4 acc3[2];
    acc3[0] = (f32x4){0.f, 0.f, 0.f, 0.f};
    acc3[1] = (f32x4){0.f, 0.f, 0.f, 0.f};
    {
        short8 a = *(const short8*)&H[wave * 16 + l16][quad * 8];
#pragma unroll
        for (int t = 0; t < 2; ++t) {
            short8 b = *(const short8*)&W23s[1][t * 16 + l16][quad * 8];
            acc3[t] = __builtin_amdgcn_mfma_f32_16x16x32_bf16(a, b, acc3[t], 0, 0, 0);
        }
    }
#pragma unroll
    for (int t = 0; t < 2; ++t) {
        int col = t * 16 + l16;
        float bv = bs3[col];
#pragma unroll
        for (int r = 0; r < 4; ++r) {
            int row = wave * 16 + quad * 4 + r;
            S[(rowBase + row) * 32 + col] = fmaxf(acc3[t][r] + bv, 0.f);
        }
    }
}

// ---------------- per-graph Gram: out[g][f][e] = sum_n S[g,n,f]*S[g,n,e] ----------------
__global__ __launch_bounds__(256) void gram(const float* __restrict__ S,
                                            float* __restrict__ out) {
    __shared__ float Sg[256 * 32];
    int t = threadIdx.x, g = blockIdx.x;
    const float4* src = (const float4*)(S + (size_t)g * 8192);
    float4* dst = (float4*)Sg;
    for (int i = 0; i < 8; ++i) dst[t + i * 256] = src[t + i * 256];
    __syncthreads();

    int f = t >> 3, e0 = (t & 7) << 2;
    float4 a = {0.f, 0.f, 0.f, 0.f};
    for (int n = 0; n < 256; ++n) {
        float sf = Sg[n * 32 + f];
        float4 se = *(const float4*)&Sg[n * 32 + e0];
        a.x += sf * se.x; a.y += sf * se.y; a.z += sf * se.z; a.w += sf * se.w;
    }
    *(float4*)(out + (size_t)g * 1024 + f * 32 + e0) = a;
}

// ---------------- per-graph MLP: 1024->32->32->2 (fp32) ----------------
__global__ __launch_bounds__(256) void graph_mlp(const float* __restrict__ HH,
                                                 const float* Wm1, const float* bm1,
                                                 const float* Wm2, const float* bm2,
                                                 const float* Wm3, const float* bm3,
                                                 float* __restrict__ out) {
    __shared__ float hh[1024];
    __shared__ float red[256];
    __shared__ float o1[32];
    __shared__ float o2[32];
    int t = threadIdx.x, g = blockIdx.x;
    ((float4*)hh)[t] = ((const float4*)(HH + (size_t)g * 1024))[t];
    __syncthreads();

    int j = t & 31, part = t >> 5;
    float p = 0.f;
    for (int i = 0; i < 128; ++i) { int k = part * 128 + i; p += hh[k] * Wm1[k * 32 + j]; }
    red[t] = p;
    __syncthreads();
    if (t < 32) {
        float s = 0.f;
        for (int q = 0; q < 8; ++q) s += red[q * 32 + t];
        o1[t] = fmaxf(s + bm1[t], 0.f);
    }
    __syncthreads();
    if (t < 32) {
        float s = 0.f;
        for (int k = 0; k < 32; ++k) s += o1[k] * Wm2[k * 32 + t];
        o2[t] = fmaxf(s + bm2[t], 0.f);
    }
    __syncthreads();
    if (t < 2) {
        float s = 0.f;
        for (int k = 0; k < 32; ++k) s += o2[k] * Wm3[k * 2 + t];
        out[524288 + g * 2 + t] = fmaxf(s + bm3[t], 0.f);
    }
}

// ---------------------------------------------------------------------------
extern "C" void kernel_launch(void* const* d_in, const int* in_sizes, int n_in,
                              void* d_out, int out_size, void* d_ws, size_t ws_size,
                              hipStream_t stream) {
    const float* x   = (const float*)d_in[0];
    const int*   ei  = (const int*)d_in[1];
    const float* W1a = (const float*)d_in[2];  const float* b1a = (const float*)d_in[3];
    const float* W2a = (const float*)d_in[4];  const float* b2a = (const float*)d_in[5];
    const float* W1b = (const float*)d_in[6];  const float* b1b = (const float*)d_in[7];
    const float* W2b = (const float*)d_in[8];  const float* b2b = (const float*)d_in[9];
    const float* Ws1 = (const float*)d_in[10]; const float* bs1 = (const float*)d_in[11];
    const float* Ws2 = (const float*)d_in[12]; const float* bs2 = (const float*)d_in[13];
    const float* Ws3 = (const float*)d_in[14]; const float* bs3 = (const float*)d_in[15];
    const float* Wm1 = (const float*)d_in[16]; const float* bm1 = (const float*)d_in[17];
    const float* Wm2 = (const float*)d_in[18]; const float* bm2 = (const float*)d_in[19];
    const float* Wm3 = (const float*)d_in[20]; const float* bm3 = (const float*)d_in[21];
    float* out = (float*)d_out;

    const int* gsrc = ei;
    const int* gdst = ei + NE;

    char* ws = (char*)d_ws;
    size_t off = 0;
    auto alloc = [&](size_t bytes) { size_t r = off; off = (off + bytes + 255) & ~(size_t)255; return r; };
    int*  cursor = (int*)(ws + alloc((size_t)NB * 4));
    u32*  ebuf   = (u32*)(ws + alloc((size_t)NB * BCAP * 4));   // 16 MB
    u16*  Wt     = (u16*)(ws + alloc(4 * 16384 * 2));
    u16*  Wsm    = (u16*)(ws + alloc(6144 * 2));
    u16*  X0     = (u16*)(ws + alloc((size_t)NN * 128 * 2));   // xb / hA / hB
    u16*  B1     = (u16*)(ws + alloc((size_t)NN * 128 * 2));   // aggregated T
    float* S     = (float*)B1;                                  // alias: B1 dead after last gemm2
    (void)ws_size; (void)n_in; (void)in_sizes; (void)out_size;

    // ---- edge binning: direct scatter into fixed bucket regions ----
    init_cursor<<<NB / 256, 256, 0, stream>>>(cursor);
    bin_scatter<<<NE / ECH, 256, 0, stream>>>(gsrc, gdst, cursor, ebuf);

    // ---- casts ----
    cast_x<<<NN * 128 / (256 * 8), 256, 0, stream>>>(x, X0);
    transpose_w<<<4, 256, 0, stream>>>(W1a, W2a, W1b, W2b, Wt);
    transpose_small<<<1, 256, 0, stream>>>(Ws1, Ws2, Ws3, Wsm);

    // ---- layer A ----
    aggregate_bucket<<<NB, 512, 0, stream>>>(X0, ebuf, cursor, B1);
    gemm2_relu<<<NN / 64, 256, 0, stream>>>(B1, Wt + 0 * 16384, Wt + 1 * 16384, b1a, b2a, X0);
    // ---- layer B ----
    aggregate_bucket<<<NB, 512, 0, stream>>>(X0, ebuf, cursor, B1);
    gemm2_relu<<<NN / 64, 256, 0, stream>>>(B1, Wt + 2 * 16384, Wt + 3 * 16384, b1b, b2b, X0);

    // ---- tail: MFMA node MLP (S aliases B1), Gram -> out, graph MLP ----
    norm_mlp_mfma<<<NN / 64, 256, 0, stream>>>(X0, Wsm, bs1, bs2, bs3, S);
    gram<<<NG, 256, 0, stream>>>(S, out);
    graph_mlp<<<NG, 256, 0, stream>>>(out, Wm1, bm1, Wm2, bm2, Wm3, bm3, out);
}